// Round 12
// baseline (71.534 us; speedup 1.0000x reference)
//
#include <hip/hip_runtime.h>
#include <hip/hip_bf16.h>

// SGCN fused: y = conv1x1(x, W)+b ; out[n,c,t,w] = sum_{k,v} y[n,k,c,t,v]*A[k,v,w]
// x:[64,64,300,25] f32, A:[3,25,25] f32, W:[64,192] f32, b:[192] f32
// d_out = [out (64*64*300*25) ; A (1875)] f32
//
// Round 12 = Round 10 (best: 60.3us, 3200 blocks, no spill) + VALU cuts:
//  (a) strength-reduced staging addressing: it=3a+b decomposition (3*256=4*192)
//      -> per-b constants (r, v, lds-base, r&7), per-a: ptr+=240000B and
//      lds_addr = lofB + ((a ^ (r&7))<<4)  [bits of 4*i2 = 4*i2_b | 16a disjoint]
//  (b) all bf16 packs via __float22bfloat162_rn (v_cvt_pk_bf16_f32), memcpy'd.
// Structure: t-outer/k-inner (8-reg acc, store per t), 2-batch staging,
// permuted-row xs so stage1 D-frag == stage2 A-frag (zero shuffle), no ys,
// bias via stage1 MFMA C-init, ONE barrier, LDS 24.5KB, (256,4).

#define TT 6
#define TCHUNKS 50
#define NB 64
#define CI 64
#define TDIM 300
#define VDIM 25
#define CO 64
#define KK 3

#define XROWS (TT*32)            // 192 rows, [192][128B] XOR swz ((r&7)<<4)
#define SMEM_BYTES (XROWS*128)   // 24576 B

#define WBUF_BYTES (KK*4*2*64*16)   // 24576: [k][wave][half][lane] 16B frags
#define ABUF_BYTES (KK*2*64*16)     //  6144: [k][nt][lane] 16B frags

typedef __attribute__((ext_vector_type(8))) short bf16x8;
typedef __attribute__((ext_vector_type(4))) float f32x4;
typedef __attribute__((ext_vector_type(4))) int i32x4;

__device__ __forceinline__ unsigned int pack2(float lo, float hi) {
    __hip_bfloat162 h = __float22bfloat162_rn(make_float2(lo, hi));  // RNE pack
    unsigned int u;
    __builtin_memcpy(&u, &h, 4);
    return u;
}
__device__ __forceinline__ unsigned short f2bf(float f) {
    __hip_bfloat16 h = __float2bfloat16(f);
    unsigned short u;
    __builtin_memcpy(&u, &h, 2);
    return u;
}

// ---- prep: bf16 B-fragments for W and A in ws; copy A to out tail ----
__global__ void sgcn_prep(const float* __restrict__ A, const float* __restrict__ W,
                          unsigned int* __restrict__ wbuf, unsigned int* __restrict__ abuf,
                          float* __restrict__ outA) {
    int id = blockIdx.x * 256 + threadIdx.x;    // grid 8*256
    if (id < KK * 4 * 2 * 64) {                 // 1536 W-fragments
        int l  = id & 63;
        int h  = (id >> 6) & 1;
        int wq = (id >> 7) & 3;
        int k  = id >> 9;
        int c  = wq * 16 + (l & 15);
        int ib = (l >> 4) * 8 + h * 32;
        unsigned int pk[4];
        #pragma unroll
        for (int j = 0; j < 4; ++j)
            pk[j] = pack2(W[(size_t)(ib + 2*j)     * (KK*CO) + k*CO + c],
                          W[(size_t)(ib + 2*j + 1) * (KK*CO) + k*CO + c]);
        *(uint4*)(wbuf + id * 4) = make_uint4(pk[0], pk[1], pk[2], pk[3]);
    }
    if (id < KK * 2 * 64) {                     // 384 A-fragments, v zero-padded to 32
        int l  = id & 63;
        int nt = (id >> 6) & 1;
        int k  = id >> 7;
        int w  = nt * 16 + (l & 15);
        int vb = (l >> 4) * 8;
        unsigned int pk[4];
        #pragma unroll
        for (int j = 0; j < 4; ++j) {
            int v0 = vb + 2*j, v1 = v0 + 1;
            unsigned short u0 = (v0 < VDIM && w < VDIM) ? f2bf(A[k*VDIM*VDIM + v0*VDIM + w]) : (unsigned short)0;
            unsigned short u1 = (v1 < VDIM && w < VDIM) ? f2bf(A[k*VDIM*VDIM + v1*VDIM + w]) : (unsigned short)0;
            pk[j] = (unsigned int)u0 | ((unsigned int)u1 << 16);
        }
        *(uint4*)(abuf + id * 4) = make_uint4(pk[0], pk[1], pk[2], pk[3]);
    }
    if (id < KK * VDIM * VDIM) outA[id] = A[id];   // tuple output 1 (exact)
}

__global__ __launch_bounds__(256, 4) void sgcn_fused(
    const float* __restrict__ x, const float* __restrict__ b,
    const unsigned int* __restrict__ wbuf, const unsigned int* __restrict__ abuf,
    float* __restrict__ out)
{
    __shared__ __align__(16) char smem[SMEM_BYTES];
    const int tid  = threadIdx.x;
    const int lane = tid & 63;
    const int wid  = tid >> 6;
    const int n    = blockIdx.y;
    const int t0   = blockIdx.x * TT;
    const int l15  = lane & 15;
    const int g    = lane >> 4;
    const int i0   = g * 8;              // K-chunk base within 32
    const int c    = wid * 16 + l15;

    // ---- staging precompute: it = 3a + b; (r, v, lds-base, mask) const per b.
    // Permuted row order: row r = t*32+rr, rr->v: v = 8*((rr&15)>>2)+4*(rr>>4)+(rr&3).
    int lofB[3], mB[3];
    const float* gpB[3];
    bool vldB[3];
    #pragma unroll
    for (int bb = 0; bb < 3; ++bb) {
        int idx = tid + bb * 256;            // < 768
        int i2b = idx / XROWS;               // 0..3
        int r   = idx - i2b * XROWS;
        int rr  = r & 31;
        int v   = ((rr & 15) >> 2) * 8 + (rr >> 4) * 4 + (rr & 3);
        vldB[bb] = (v < VDIM);
        mB[bb]   = r & 7;
        lofB[bb] = r * 128 + 4 * i2b;
        gpB[bb]  = x + (((size_t)n * CI + 2 * i2b) * TDIM + (t0 + (r >> 5))) * VDIM + v;
    }

    // ---- staging, 2 batches (a = bat*4 .. bat*4+3): load 12, then pack+write 12.
    float s0[12], s1[12];
    #pragma unroll 1
    for (int bat = 0; bat < 2; ++bat) {
        #pragma unroll
        for (int a4 = 0; a4 < 4; ++a4) {
            int a = bat * 4 + a4;
            #pragma unroll
            for (int bb = 0; bb < 3; ++bb) {
                int si = a4 * 3 + bb;
                const float* p = gpB[bb] + (size_t)a * (8 * TDIM * VDIM);  // ch += 8 per a
                s0[si] = vldB[bb] ? p[0] : 0.f;
                s1[si] = vldB[bb] ? p[(size_t)TDIM * VDIM] : 0.f;
            }
        }
        #pragma unroll
        for (int a4 = 0; a4 < 4; ++a4) {
            int a = bat * 4 + a4;
            #pragma unroll
            for (int bb = 0; bb < 3; ++bb) {
                int si = a4 * 3 + bb;
                int addr = lofB[bb] + ((a ^ mB[bb]) << 4);
                *(unsigned int*)(smem + addr) = pack2(s0[si], s1[si]);
            }
        }
    }
    __syncthreads();   // the ONLY barrier

    // ---- hoist all W/A fragments + bias (L2-resident) ----
    bf16x8 WB[KK][2], AB[KK][2];
    float bv[KK];
    #pragma unroll
    for (int k = 0; k < KK; ++k) {
        WB[k][0] = *(const bf16x8*)(wbuf + (((k*4 + wid)*2 + 0)*64 + lane)*4);
        WB[k][1] = *(const bf16x8*)(wbuf + (((k*4 + wid)*2 + 1)*64 + lane)*4);
        AB[k][0] = *(const bf16x8*)(abuf + ((k*2 + 0)*64 + lane)*4);
        AB[k][1] = *(const bf16x8*)(abuf + ((k*2 + 1)*64 + lane)*4);
        bv[k]    = b[k*CO + c];
    }

    const size_t cs = (size_t)TDIM * VDIM;   // out stride for c+1
    #pragma unroll
    for (int t = 0; t < TT; ++t) {
        // A-frags for this t (reused across all k)
        int j0 = t*32 + l15;
        int j1 = j0 + 16;
        const char* p0 = smem + j0*128;
        const char* p1 = smem + j1*128;
        bf16x8 A00 = *(const bf16x8*)(p0 + ((2*i0)      ^ ((j0 & 7) << 4)));
        bf16x8 A01 = *(const bf16x8*)(p0 + ((2*i0 + 64) ^ ((j0 & 7) << 4)));
        bf16x8 A10 = *(const bf16x8*)(p1 + ((2*i0)      ^ ((j1 & 7) << 4)));
        bf16x8 A11 = *(const bf16x8*)(p1 + ((2*i0 + 64) ^ ((j1 & 7) << 4)));

        f32x4 accA = {0.f, 0.f, 0.f, 0.f};
        f32x4 accB = {0.f, 0.f, 0.f, 0.f};
        #pragma unroll
        for (int k = 0; k < KK; ++k) {
            f32x4 D0 = {bv[k], bv[k], bv[k], bv[k]};   // bias via C-operand
            f32x4 D1 = D0;
            D0 = __builtin_amdgcn_mfma_f32_16x16x32_bf16(A00, WB[k][0], D0, 0, 0, 0);
            D0 = __builtin_amdgcn_mfma_f32_16x16x32_bf16(A01, WB[k][1], D0, 0, 0, 0);
            D1 = __builtin_amdgcn_mfma_f32_16x16x32_bf16(A10, WB[k][0], D1, 0, 0, 0);
            D1 = __builtin_amdgcn_mfma_f32_16x16x32_bf16(A11, WB[k][1], D1, 0, 0, 0);
            // lane holds y[c][v]: D0 -> v=8g+{0..3}, D1 -> v=8g+4+{0..3}
            // == exactly the stage2 A-fragment (k-elements 8g..8g+7).
            i32x4 pav = {(int)pack2(D0.x, D0.y), (int)pack2(D0.z, D0.w),
                         (int)pack2(D1.x, D1.y), (int)pack2(D1.z, D1.w)};
            bf16x8 PA = __builtin_bit_cast(bf16x8, pav);
            accA = __builtin_amdgcn_mfma_f32_16x16x32_bf16(PA, AB[k][0], accA, 0, 0, 0);
            accB = __builtin_amdgcn_mfma_f32_16x16x32_bf16(PA, AB[k][1], accB, 0, 0, 0);
        }
        // ---- store this t: D2 col=w=l15(+16*nt), rows c = wid*16 + 4g + p ----
        size_t base = (((size_t)n * CO + (wid*16 + 4*g)) * TDIM + (t0 + t)) * VDIM + l15;
        out[base]        = accA.x;
        out[base + cs]   = accA.y;
        out[base + 2*cs] = accA.z;
        out[base + 3*cs] = accA.w;
        if (l15 < VDIM - 16) {
            size_t base2 = base + 16;
            out[base2]        = accB.x;
            out[base2 + cs]   = accB.y;
            out[base2 + 2*cs] = accB.z;
            out[base2 + 3*cs] = accB.w;
        }
    }
}

extern "C" void kernel_launch(void* const* d_in, const int* in_sizes, int n_in,
                              void* d_out, int out_size, void* d_ws, size_t ws_size,
                              hipStream_t stream) {
    const float* x = (const float*)d_in[0];
    const float* A = (const float*)d_in[1];
    const float* W = (const float*)d_in[2];
    const float* b = (const float*)d_in[3];
    float* out = (float*)d_out;

    unsigned int* wbuf = (unsigned int*)d_ws;
    unsigned int* abuf = (unsigned int*)((char*)d_ws + WBUF_BYTES);

    const size_t out_elems = (size_t)NB * CO * TDIM * VDIM;
    sgcn_prep<<<8, 256, 0, stream>>>(A, W, wbuf, abuf, out + out_elems);

    dim3 grid(TCHUNKS, NB);
    sgcn_fused<<<grid, 256, 0, stream>>>(x, b, wbuf, abuf, out);
}

// Round 13
// 57.021 us; speedup vs baseline: 1.2545x; 1.2545x over previous
//
#include <hip/hip_runtime.h>
#include <hip/hip_bf16.h>

// SGCN fused: y = conv1x1(x, W)+b ; out[n,c,t,w] = sum_{k,v} y[n,k,c,t,v]*A[k,v,w]
// x:[64,64,300,25] f32, A:[3,25,25] f32, W:[64,192] f32, b:[192] f32
// d_out = [out (64*64*300*25) ; A (1875)] f32
//
// Round 13 = Round 10 structure + float4 staging:
// key property: 4 consecutive v (v0=4*grp) map to 4 CONSECUTIVE permuted rows
// (rr=16h+4a+p, grp=2a+h), so one float4 load per channel replaces 4 scalars.
// 48 -> 12 load instrs/thread, 16B/lane coalescing. Guards are exec-masked
// `if` (r12 lesson: ternary-selects serialized the load batch, 89->117us).
// v0<=20 float4 in-bounds; v0=24 scalar (OOB guard at array end); v0=28 zeros.
// Structure: t-outer/k-inner (8-reg acc, store per t), 2-batch staging,
// permuted-row xs so stage1 D-frag == stage2 A-frag (zero shuffle), no ys,
// bias via stage1 MFMA C-init, ONE barrier, LDS 24.5KB, (256,4).

#define TT 6
#define TCHUNKS 50
#define NB 64
#define CI 64
#define TDIM 300
#define VDIM 25
#define CO 64
#define KK 3

#define XROWS (TT*32)            // 192 rows, [192][128B] XOR swz ((r&7)<<4)
#define SMEM_BYTES (XROWS*128)   // 24576 B

#define WBUF_BYTES (KK*4*2*64*16)   // 24576: [k][wave][half][lane] 16B frags
#define ABUF_BYTES (KK*2*64*16)     //  6144: [k][nt][lane] 16B frags

typedef __attribute__((ext_vector_type(8))) short bf16x8;
typedef __attribute__((ext_vector_type(4))) float f32x4;
typedef __attribute__((ext_vector_type(4))) int i32x4;
typedef __attribute__((ext_vector_type(4), aligned(4))) float f32x4u;  // 4B-aligned vec load

__device__ __forceinline__ unsigned int pack2(float lo, float hi) {
    __hip_bfloat162 h = __float22bfloat162_rn(make_float2(lo, hi));  // v_cvt_pk_bf16_f32
    unsigned int u;
    __builtin_memcpy(&u, &h, 4);
    return u;
}
__device__ __forceinline__ unsigned short f2bf(float f) {
    __hip_bfloat16 h = __float2bfloat16(f);
    unsigned short u;
    __builtin_memcpy(&u, &h, 2);
    return u;
}

// ---- prep: bf16 B-fragments for W and A in ws; copy A to out tail ----
__global__ void sgcn_prep(const float* __restrict__ A, const float* __restrict__ W,
                          unsigned int* __restrict__ wbuf, unsigned int* __restrict__ abuf,
                          float* __restrict__ outA) {
    int id = blockIdx.x * 256 + threadIdx.x;    // grid 8*256
    if (id < KK * 4 * 2 * 64) {                 // 1536 W-fragments
        int l  = id & 63;
        int h  = (id >> 6) & 1;
        int wq = (id >> 7) & 3;
        int k  = id >> 9;
        int c  = wq * 16 + (l & 15);
        int ib = (l >> 4) * 8 + h * 32;
        unsigned int pk[4];
        #pragma unroll
        for (int j = 0; j < 4; ++j)
            pk[j] = pack2(W[(size_t)(ib + 2*j)     * (KK*CO) + k*CO + c],
                          W[(size_t)(ib + 2*j + 1) * (KK*CO) + k*CO + c]);
        *(uint4*)(wbuf + id * 4) = make_uint4(pk[0], pk[1], pk[2], pk[3]);
    }
    if (id < KK * 2 * 64) {                     // 384 A-fragments, v zero-padded to 32
        int l  = id & 63;
        int nt = (id >> 6) & 1;
        int k  = id >> 7;
        int w  = nt * 16 + (l & 15);
        int vb = (l >> 4) * 8;
        unsigned int pk[4];
        #pragma unroll
        for (int j = 0; j < 4; ++j) {
            int v0 = vb + 2*j, v1 = v0 + 1;
            unsigned short u0 = (v0 < VDIM && w < VDIM) ? f2bf(A[k*VDIM*VDIM + v0*VDIM + w]) : (unsigned short)0;
            unsigned short u1 = (v1 < VDIM && w < VDIM) ? f2bf(A[k*VDIM*VDIM + v1*VDIM + w]) : (unsigned short)0;
            pk[j] = (unsigned int)u0 | ((unsigned int)u1 << 16);
        }
        *(uint4*)(abuf + id * 4) = make_uint4(pk[0], pk[1], pk[2], pk[3]);
    }
    if (id < KK * VDIM * VDIM) outA[id] = A[id];   // tuple output 1 (exact)
}

__global__ __launch_bounds__(256, 4) void sgcn_fused(
    const float* __restrict__ x, const float* __restrict__ b,
    const unsigned int* __restrict__ wbuf, const unsigned int* __restrict__ abuf,
    float* __restrict__ out)
{
    __shared__ __align__(16) char smem[SMEM_BYTES];
    const int tid  = threadIdx.x;
    const int lane = tid & 63;
    const int wid  = tid >> 6;
    const int n    = blockIdx.y;
    const int t0   = blockIdx.x * TT;
    const int l15  = lane & 15;
    const int g    = lane >> 4;
    const int i0   = g * 8;              // K-chunk base within 32
    const int c    = wid * 16 + l15;

    // ---- staging: task id = tid + it*256, it=0..5 over 1536 tasks.
    // id -> i2 = id/48, rem = id%48, t = rem>>3, grp = rem&7.
    // grp -> (a = grp>>1, h = grp&1): v0 = 4*grp = 8a+4h; rows rr = 16h+4a+p.
    // One float4 per channel covers v0..v0+3 -> 4 consecutive permuted rows.
    f32x4 q0[3], q1[3];
    #pragma unroll 1
    for (int bat = 0; bat < 2; ++bat) {
        #pragma unroll
        for (int j = 0; j < 3; ++j) {
            int id  = tid + (bat * 3 + j) * 256;
            int i2  = id / 48;
            int rem = id - i2 * 48;
            int t   = rem >> 3;
            int grp = rem & 7;
            const float* pc0 = x + (((size_t)n * CI + 2*i2) * TDIM + (t0 + t)) * VDIM + 4*grp;
            const float* pc1 = pc0 + TDIM * VDIM;
            q0[j] = (f32x4){0.f, 0.f, 0.f, 0.f};
            q1[j] = (f32x4){0.f, 0.f, 0.f, 0.f};
            if (grp < 6) {                       // v0<=20: float4 fully valid
                q0[j] = *(const f32x4u*)pc0;
                q1[j] = *(const f32x4u*)pc1;
            } else if (grp == 6) {               // v0=24: only v=24 valid
                q0[j].x = pc0[0];
                q1[j].x = pc1[0];
            }                                    // grp==7: zeros
        }
        #pragma unroll
        for (int j = 0; j < 3; ++j) {
            int id  = tid + (bat * 3 + j) * 256;
            int i2  = id / 48;
            int rem = id - i2 * 48;
            int t   = rem >> 3;
            int grp = rem & 7;
            int rr0 = ((grp & 1) << 4) + ((grp >> 1) << 2);   // 16h + 4a
            int rbase = t * 32 + rr0;
            int m   = rr0 & 7;                                 // in {0,4}
            #pragma unroll
            for (int p = 0; p < 4; ++p) {
                int addr = (rbase + p) * 128 + ((4*i2) ^ ((m + p) << 4));
                *(unsigned int*)(smem + addr) = pack2(q0[j][p], q1[j][p]);
            }
        }
    }
    __syncthreads();   // the ONLY barrier

    // ---- hoist all W/A fragments + bias (L2-resident) ----
    bf16x8 WB[KK][2], AB[KK][2];
    float bv[KK];
    #pragma unroll
    for (int k = 0; k < KK; ++k) {
        WB[k][0] = *(const bf16x8*)(wbuf + (((k*4 + wid)*2 + 0)*64 + lane)*4);
        WB[k][1] = *(const bf16x8*)(wbuf + (((k*4 + wid)*2 + 1)*64 + lane)*4);
        AB[k][0] = *(const bf16x8*)(abuf + ((k*2 + 0)*64 + lane)*4);
        AB[k][1] = *(const bf16x8*)(abuf + ((k*2 + 1)*64 + lane)*4);
        bv[k]    = b[k*CO + c];
    }

    const size_t cs = (size_t)TDIM * VDIM;   // out stride for c+1
    #pragma unroll
    for (int t = 0; t < TT; ++t) {
        // A-frags for this t (reused across all k)
        int j0 = t*32 + l15;
        int j1 = j0 + 16;
        const char* p0 = smem + j0*128;
        const char* p1 = smem + j1*128;
        bf16x8 A00 = *(const bf16x8*)(p0 + ((2*i0)      ^ ((j0 & 7) << 4)));
        bf16x8 A01 = *(const bf16x8*)(p0 + ((2*i0 + 64) ^ ((j0 & 7) << 4)));
        bf16x8 A10 = *(const bf16x8*)(p1 + ((2*i0)      ^ ((j1 & 7) << 4)));
        bf16x8 A11 = *(const bf16x8*)(p1 + ((2*i0 + 64) ^ ((j1 & 7) << 4)));

        f32x4 accA = {0.f, 0.f, 0.f, 0.f};
        f32x4 accB = {0.f, 0.f, 0.f, 0.f};
        #pragma unroll
        for (int k = 0; k < KK; ++k) {
            f32x4 D0 = {bv[k], bv[k], bv[k], bv[k]};   // bias via C-operand
            f32x4 D1 = D0;
            D0 = __builtin_amdgcn_mfma_f32_16x16x32_bf16(A00, WB[k][0], D0, 0, 0, 0);
            D0 = __builtin_amdgcn_mfma_f32_16x16x32_bf16(A01, WB[k][1], D0, 0, 0, 0);
            D1 = __builtin_amdgcn_mfma_f32_16x16x32_bf16(A10, WB[k][0], D1, 0, 0, 0);
            D1 = __builtin_amdgcn_mfma_f32_16x16x32_bf16(A11, WB[k][1], D1, 0, 0, 0);
            // lane holds y[c][v]: D0 -> v=8g+{0..3}, D1 -> v=8g+4+{0..3}
            // == exactly the stage2 A-fragment (k-elements 8g..8g+7).
            i32x4 pav = {(int)pack2(D0.x, D0.y), (int)pack2(D0.z, D0.w),
                         (int)pack2(D1.x, D1.y), (int)pack2(D1.z, D1.w)};
            bf16x8 PA = __builtin_bit_cast(bf16x8, pav);
            accA = __builtin_amdgcn_mfma_f32_16x16x32_bf16(PA, AB[k][0], accA, 0, 0, 0);
            accB = __builtin_amdgcn_mfma_f32_16x16x32_bf16(PA, AB[k][1], accB, 0, 0, 0);
        }
        // ---- store this t: D2 col=w=l15(+16*nt), rows c = wid*16 + 4g + p ----
        size_t base = (((size_t)n * CO + (wid*16 + 4*g)) * TDIM + (t0 + t)) * VDIM + l15;
        out[base]        = accA.x;
        out[base + cs]   = accA.y;
        out[base + 2*cs] = accA.z;
        out[base + 3*cs] = accA.w;
        if (l15 < VDIM - 16) {
            size_t base2 = base + 16;
            out[base2]        = accB.x;
            out[base2 + cs]   = accB.y;
            out[base2 + 2*cs] = accB.z;
            out[base2 + 3*cs] = accB.w;
        }
    }
}

extern "C" void kernel_launch(void* const* d_in, const int* in_sizes, int n_in,
                              void* d_out, int out_size, void* d_ws, size_t ws_size,
                              hipStream_t stream) {
    const float* x = (const float*)d_in[0];
    const float* A = (const float*)d_in[1];
    const float* W = (const float*)d_in[2];
    const float* b = (const float*)d_in[3];
    float* out = (float*)d_out;

    unsigned int* wbuf = (unsigned int*)d_ws;
    unsigned int* abuf = (unsigned int*)((char*)d_ws + WBUF_BYTES);

    const size_t out_elems = (size_t)NB * CO * TDIM * VDIM;
    sgcn_prep<<<8, 256, 0, stream>>>(A, W, wbuf, abuf, out + out_elems);

    dim3 grid(TCHUNKS, NB);
    sgcn_fused<<<grid, 256, 0, stream>>>(x, b, wbuf, abuf, out);
}